// Round 2
// baseline (36.592 us; speedup 1.0000x reference)
//
#include <hip/hip_runtime.h>

// ParallelCheby2D: out[b,t] = sum_{i=0..3} x[b,t-i] * g_i(t)
//   g_i = sum_{j=0..3} sum_{p,q} (w_r + i*w_i)[4i+j][p][q] * T_p(|x[t-i]|) * T_q(|x[t-j]|)
// B=4, T=131072, ORDER=8; branch n has delays d_out=d_in1=n>>2, d_in2=n&3.
//
// Harness output contract (deduced from out_npz_mb≈2.05 and round-1 OOB abort):
// d_out holds out_size float32 elements. out_size==B*T -> real part only;
// out_size==2*B*T -> complex64 interleaved. Both paths supported; stores never
// exceed out_size floats.

static constexpr int T_LEN = 131072;  // 2^17

template <bool WRITE_COMPLEX>
__global__ __launch_bounds__(256) void cheby2d_kernel(
    const float* __restrict__ xr_g, const float* __restrict__ xi_g,
    const float* __restrict__ wr_g, const float* __restrict__ wi_g,
    float* __restrict__ out, int total)
{
    const int idx = blockIdx.x * 256 + threadIdx.x;
    if (idx >= total) return;
    const int t = idx & (T_LEN - 1);

    // Delayed taps (zero-padded at sequence start, per batch row) + magnitudes.
    float xr[4], xi[4], r[4];
#pragma unroll
    for (int i = 0; i < 4; ++i) {
        float a = 0.f, b = 0.f;
        if (t >= i) { a = xr_g[idx - i]; b = xi_g[idx - i]; }
        xr[i] = a; xi[i] = b;
        r[i] = sqrtf(fmaf(a, a, b * b));
    }

    // Chebyshev values C[j][q] = T_q(r[j]), q = 0..7.
    float C[4][8];
#pragma unroll
    for (int j = 0; j < 4; ++j) {
        C[j][0] = 1.f;
        C[j][1] = r[j];
        const float tr2 = r[j] + r[j];
#pragma unroll
        for (int q = 2; q < 8; ++q)
            C[j][q] = fmaf(tr2, C[j][q - 1], -C[j][q - 2]);
    }

    // u[i][p] = sum_j sum_q w[4i+j][p][q] * C[j][q]
    float ur[4][8], ui[4][8];
#pragma unroll
    for (int i = 0; i < 4; ++i)
#pragma unroll
        for (int p = 0; p < 8; ++p) { ur[i][p] = 0.f; ui[i][p] = 0.f; }

#pragma unroll
    for (int i = 0; i < 4; ++i) {
#pragma unroll
        for (int j = 0; j < 4; ++j) {
            const int wb = ((i << 2) + j) << 6;  // branch n = 4i+j, 64 floats
#pragma unroll
            for (int p = 0; p < 8; ++p) {
                const int off = wb + (p << 3);
#pragma unroll
                for (int q = 0; q < 8; ++q) {   // contiguous -> s_load friendly
                    ur[i][p] = fmaf(wr_g[off + q], C[j][q], ur[i][p]);
                    if (WRITE_COMPLEX)
                        ui[i][p] = fmaf(wi_g[off + q], C[j][q], ui[i][p]);
                }
            }
        }
    }

    // G_i = C_i . u_i ; out = sum_i x[t-i] * G_i (complex mac)
    float outr = 0.f, outi = 0.f;
#pragma unroll
    for (int i = 0; i < 4; ++i) {
        float gr = 0.f, gm = 0.f;
#pragma unroll
        for (int p = 0; p < 8; ++p) {
            gr = fmaf(C[i][p], ur[i][p], gr);
            if (WRITE_COMPLEX) gm = fmaf(C[i][p], ui[i][p], gm);
        }
        outr = fmaf(xr[i], gr, outr);
        if (WRITE_COMPLEX) {
            outr = fmaf(-xi[i], gm, outr);
            outi = fmaf(xr[i], gm, outi);
            outi = fmaf(xi[i], gr, outi);
        } else {
            // real part of x*conj? No: real(x*g) = xr*gr - xi*gi, but gi needs
            // imag weights. Real-only output still needs the imag-gain term:
            // handled below in the complex==false specialization via gi path.
        }
    }

    if (WRITE_COMPLEX) {
        reinterpret_cast<float2*>(out)[idx] = make_float2(outr, outi);
    } else {
        out[idx] = outr;
    }
}

// Real-part-only output still depends on imaginary gains:
//   real(out) = sum_i [ xr_i * gr_i - xi_i * gi_i ]
// so the real-only kernel must compute BOTH weight halves but store one float.
__global__ __launch_bounds__(256) void cheby2d_real_kernel(
    const float* __restrict__ xr_g, const float* __restrict__ xi_g,
    const float* __restrict__ wr_g, const float* __restrict__ wi_g,
    float* __restrict__ out, int total)
{
    const int idx = blockIdx.x * 256 + threadIdx.x;
    if (idx >= total) return;
    const int t = idx & (T_LEN - 1);

    float xr[4], xi[4], r[4];
#pragma unroll
    for (int i = 0; i < 4; ++i) {
        float a = 0.f, b = 0.f;
        if (t >= i) { a = xr_g[idx - i]; b = xi_g[idx - i]; }
        xr[i] = a; xi[i] = b;
        r[i] = sqrtf(fmaf(a, a, b * b));
    }

    float C[4][8];
#pragma unroll
    for (int j = 0; j < 4; ++j) {
        C[j][0] = 1.f;
        C[j][1] = r[j];
        const float tr2 = r[j] + r[j];
#pragma unroll
        for (int q = 2; q < 8; ++q)
            C[j][q] = fmaf(tr2, C[j][q - 1], -C[j][q - 2]);
    }

    float ur[4][8], ui[4][8];
#pragma unroll
    for (int i = 0; i < 4; ++i)
#pragma unroll
        for (int p = 0; p < 8; ++p) { ur[i][p] = 0.f; ui[i][p] = 0.f; }

#pragma unroll
    for (int i = 0; i < 4; ++i) {
#pragma unroll
        for (int j = 0; j < 4; ++j) {
            const int wb = ((i << 2) + j) << 6;
#pragma unroll
            for (int p = 0; p < 8; ++p) {
                const int off = wb + (p << 3);
#pragma unroll
                for (int q = 0; q < 8; ++q) {
                    ur[i][p] = fmaf(wr_g[off + q], C[j][q], ur[i][p]);
                    ui[i][p] = fmaf(wi_g[off + q], C[j][q], ui[i][p]);
                }
            }
        }
    }

    float outr = 0.f;
#pragma unroll
    for (int i = 0; i < 4; ++i) {
        float gr = 0.f, gm = 0.f;
#pragma unroll
        for (int p = 0; p < 8; ++p) {
            gr = fmaf(C[i][p], ur[i][p], gr);
            gm = fmaf(C[i][p], ui[i][p], gm);
        }
        outr = fmaf(xr[i], gr, outr);
        outr = fmaf(-xi[i], gm, outr);
    }
    out[idx] = outr;
}

extern "C" void kernel_launch(void* const* d_in, const int* in_sizes, int n_in,
                              void* d_out, int out_size, void* d_ws, size_t ws_size,
                              hipStream_t stream) {
    const float* xr = (const float*)d_in[0];   // [B,1,T] float32
    const float* xi = (const float*)d_in[1];   // [B,1,T] float32
    const float* wr = (const float*)d_in[2];   // [16,8,8] float32
    const float* wi = (const float*)d_in[3];   // [16,8,8] float32
    float* out = (float*)d_out;

    const int total = in_sizes[0];             // B*T = 524288
    const int blocks = (total + 255) / 256;

    if (out_size >= 2 * total) {
        // complex64 interleaved layout
        cheby2d_kernel<true><<<blocks, 256, 0, stream>>>(xr, xi, wr, wi, out, total);
    } else {
        // real-part-only float32 layout (out_size == total)
        cheby2d_real_kernel<<<blocks, 256, 0, stream>>>(xr, xi, wr, wi, out, total);
    }
}